// Round 8
// baseline (22.334 us; speedup 1.0000x reference)
//
#include <hip/hip_runtime.h>

#define BATCH 16
#define LEN 512
#define HID 384
#define TOUT 3584            // LEN * (DUR_MAX-1) = 512*7
#define VEC (HID / 4)        // 96 float4 per output row
#define TPB 512              // threads per block (= LEN, one elem each for scan)
#define NWAVE (TPB / 64)     // 8 waves
#define T_TILE 112           // output timesteps per block; TOUT/T_TILE = 32
                             // -> grid = 32*16 = 512 blocks = exactly 2/CU
#define ITERS ((T_TILE * VEC) / TPB)   // 21 float4 per thread

typedef float f32x4 __attribute__((ext_vector_type(4)));

// Fused kernel, per-block (b, 112-timestep tile):
//   phase 1: wave-shuffle inclusive scan of durations[b,:] (2 barriers)
//   phase 2: binary search for the tile's 112 timesteps -> sidx / mask
//   phase 3: max-MLP gather: issue ALL 21 gather loads, then ALL 21 stores.
//            __launch_bounds__(512,4) caps VGPR at 128 -> 2 blocks/CU stay
//            co-resident. (NT stores measured -10% in R4; plain stores.)
__global__ void __launch_bounds__(TPB, 4)
fused_length_regulator(const f32x4* __restrict__ ehs,
                       const int* __restrict__ dur,
                       f32x4* __restrict__ out,
                       float* __restrict__ mask_out) {
    __shared__ int s[LEN];
    __shared__ int wsum[NWAVE];
    __shared__ int sidx[T_TILE];

    const int b    = blockIdx.y;
    const int tid  = threadIdx.x;
    const int lane = tid & 63;
    const int wid  = tid >> 6;

    // phase 1: inclusive cumsum via wave shuffles + wave-sum prefix.
    int v = dur[b * LEN + tid];
    #pragma unroll
    for (int off = 1; off < 64; off <<= 1) {
        int n = __shfl_up(v, off, 64);
        if (lane >= off) v += n;
    }
    if (lane == 63) wsum[wid] = v;
    __syncthreads();
    int add = 0;
    #pragma unroll
    for (int w = 0; w < NWAVE; ++w)
        if (w < wid) add += wsum[w];
    v += add;
    s[tid] = v;
    __syncthreads();

    // phase 2: searchsorted(cs, t, side='right') for this block's 112 t's.
    const int t0 = blockIdx.x * T_TILE;
    if (tid < T_TILE) {
        const int t = t0 + tid;
        const int total = s[LEN - 1];
        int lo = 0, hi = LEN;
        while (lo < hi) {
            int mid = (lo + hi) >> 1;
            if (s[mid] <= t) lo = mid + 1; else hi = mid;
        }
        int idx = lo < (LEN - 1) ? lo : (LEN - 1);
        const bool m = t < total;
        sidx[tid] = m ? idx : -1;
        mask_out[b * TOUT + t] = m ? 1.0f : 0.0f;
    }
    __syncthreads();

    // phase 3: gather indices -> regs (static after unroll), then issue all
    // loads back-to-back (deep MLP), then drain all stores.
    const f32x4* __restrict__ src_b = ehs + (long long)b * LEN * VEC;
    f32x4* __restrict__ dst = out + ((long long)b * TOUT + t0) * VEC;

    int roff[ITERS];     // source offset in float4 units, or -1 if masked
    #pragma unroll
    for (int it = 0; it < ITERS; ++it) {
        const int j = it * TPB + tid;
        const int r = j / VEC;
        const int c = j - r * VEC;
        const int iv = sidx[r];
        roff[it] = (iv >= 0) ? (iv * VEC + c) : -1;
    }

    f32x4 buf[ITERS];
    #pragma unroll
    for (int it = 0; it < ITERS; ++it) {
        const int o = roff[it];
        buf[it] = (o >= 0) ? src_b[o] : (f32x4)(0.f);
    }

    #pragma unroll
    for (int it = 0; it < ITERS; ++it)
        dst[it * TPB + tid] = buf[it];
}

extern "C" void kernel_launch(void* const* d_in, const int* in_sizes, int n_in,
                              void* d_out, int out_size, void* d_ws, size_t ws_size,
                              hipStream_t stream) {
    const float* ehs = (const float*)d_in[0];
    const int* dur   = (const int*)d_in[1];
    // d_in[2] = max_durations scalar; compile-time constant TOUT used.

    float* out_expanded = (float*)d_out;                                  // [B,T,H]
    float* out_mask     = (float*)d_out + (long long)BATCH * TOUT * HID;  // [B,T]

    dim3 grid(TOUT / T_TILE, BATCH);   // 32 x 16 = 512 blocks, 2 per CU
    fused_length_regulator<<<grid, TPB, 0, stream>>>(
        (const f32x4*)ehs, dur, (f32x4*)out_expanded, out_mask);
}

// Round 9
// 20.743 us; speedup vs baseline: 1.0767x; 1.0767x over previous
//
#include <hip/hip_runtime.h>

#define BATCH 16
#define LEN 512
#define HID 384
#define TOUT 3584            // LEN * (DUR_MAX-1) = 512*7
#define VEC (HID / 4)        // 96 float4 per output row
#define TPB 512              // threads per block (= LEN, one elem each for scan)
#define NWAVE (TPB / 64)     // 8 waves
#define T_TILE 112           // output timesteps per block; TOUT/T_TILE = 32
                             // -> grid = 32*16 = 512 blocks = exactly 2/CU

typedef float f32x4 __attribute__((ext_vector_type(4)));

// Fused kernel, per-block (b, 112-timestep tile). Best-measured config (R7,
// 20.84 us):
//   phase 1: wave-shuffle inclusive scan of durations[b,:] (2 barriers)
//   phase 2: binary search for the tile's 112 timesteps -> sidx / mask
//   phase 3: stream 112*96 float4 gathered writes, compiler-scheduled loop.
// Tested and rejected: NT stores (-10%, bypass L2 write buffering);
// manual load-all/store-all MLP split (-7%, VGPR pressure);
// T_TILE 64/128 (neutral); 3-kernel split (+33%, launch gaps).
__global__ void __launch_bounds__(TPB)
fused_length_regulator(const f32x4* __restrict__ ehs,
                       const int* __restrict__ dur,
                       f32x4* __restrict__ out,
                       float* __restrict__ mask_out) {
    __shared__ int s[LEN];
    __shared__ int wsum[NWAVE];
    __shared__ int sidx[T_TILE];

    const int b    = blockIdx.y;
    const int tid  = threadIdx.x;
    const int lane = tid & 63;
    const int wid  = tid >> 6;

    // phase 1: inclusive cumsum via wave shuffles + wave-sum prefix.
    int v = dur[b * LEN + tid];
    #pragma unroll
    for (int off = 1; off < 64; off <<= 1) {
        int n = __shfl_up(v, off, 64);
        if (lane >= off) v += n;
    }
    if (lane == 63) wsum[wid] = v;
    __syncthreads();
    int add = 0;
    #pragma unroll
    for (int w = 0; w < NWAVE; ++w)
        if (w < wid) add += wsum[w];
    v += add;
    s[tid] = v;
    __syncthreads();

    // phase 2: searchsorted(cs, t, side='right') for this block's 112 t's.
    const int t0 = blockIdx.x * T_TILE;
    if (tid < T_TILE) {
        const int t = t0 + tid;
        const int total = s[LEN - 1];
        int lo = 0, hi = LEN;
        while (lo < hi) {
            int mid = (lo + hi) >> 1;
            if (s[mid] <= t) lo = mid + 1; else hi = mid;
        }
        int idx = lo < (LEN - 1) ? lo : (LEN - 1);
        const bool m = t < total;
        sidx[tid] = m ? idx : -1;
        mask_out[b * TOUT + t] = m ? 1.0f : 0.0f;
    }
    __syncthreads();

    // phase 3: gathered streaming copy, 112 rows x 96 float4 = 10752 float4.
    const f32x4* __restrict__ src_b = ehs + (long long)b * LEN * VEC;
    f32x4* __restrict__ dst = out + ((long long)b * TOUT + t0) * VEC;
    #pragma unroll
    for (int it = 0; it < (T_TILE * VEC) / TPB; ++it) {   // 21 iterations
        const int j = it * TPB + tid;
        const int r = j / VEC;            // magic-mul, cheap
        const int c = j - r * VEC;
        const int iv = sidx[r];
        f32x4 val = (f32x4)(0.f);
        if (iv >= 0) val = src_b[iv * VEC + c];
        dst[j] = val;
    }
}

extern "C" void kernel_launch(void* const* d_in, const int* in_sizes, int n_in,
                              void* d_out, int out_size, void* d_ws, size_t ws_size,
                              hipStream_t stream) {
    const float* ehs = (const float*)d_in[0];
    const int* dur   = (const int*)d_in[1];
    // d_in[2] = max_durations scalar; compile-time constant TOUT used.

    float* out_expanded = (float*)d_out;                                  // [B,T,H]
    float* out_mask     = (float*)d_out + (long long)BATCH * TOUT * HID;  // [B,T]

    dim3 grid(TOUT / T_TILE, BATCH);   // 32 x 16 = 512 blocks, 2 per CU
    fused_length_regulator<<<grid, TPB, 0, stream>>>(
        (const f32x4*)ehs, dur, (f32x4*)out_expanded, out_mask);
}